// Round 4
// baseline (2883.038 us; speedup 1.0000x reference)
//
#include <hip/hip_runtime.h>
#include <cmath>

#ifndef M_PI
#define M_PI 3.14159265358979323846
#endif

#define K_CHEB 48
#define A_CHEB 0.065
#define B_CHEB 12.5
#define PS_S 4
#define PS_Q 12

typedef __attribute__((ext_vector_type(8))) short bhalf8;
typedef __attribute__((ext_vector_type(16))) float f32x16;

struct PS4 {
  float mid, invhalf;
  float a[PS_Q + 1][PS_S];   // a[q][r]: G_q = sum_r a[q][r] T_r(What)
};

// ---------- cheap bf16 helpers (round-to-nearest, ties up: unbiased for continuous data) ----------

__device__ __forceinline__ short bfh(float x) {
  return (short)((__float_as_uint(x) + 0x8000u) >> 16);
}

// ---------- fragment-major LDS layout ----------
// A 64x64 matrix Z staged "naturally" (thread covers stored-row c, k-chunk) keeps
// Z[c][k] at addr(c,k) = ((c>>5)<<11) | ((k>>4)<<9) | (((k>>3)&1)<<8) | ((c&31)<<3) | (k&7).
// 12 bits, bijective on [0,4096). MFMA reads: B-frag (lane ln=n, hf) -> B[k][n] = Z[n][k];
// A-frag -> A[m][k] = Z[m][k]. tstore of a product result v writes v[m][n] at addr(n, m),
// so the buffer acts as B = v (exact) and A = v^T (use only on ~symmetric v).
// All frag reads: 16B-lane-stride b128, conflict-free; tstores: contiguous 8B-chunk permutation.

__device__ __forceinline__ f32x16 gemmA(const bhalf8 a[4], const short* __restrict__ B, int boff) {
  f32x16 acc;
#pragma unroll
  for (int t = 0; t < 16; t++) acc[t] = 0.f;
#pragma unroll
  for (int kb = 0; kb < 4; kb++)
    acc = __builtin_amdgcn_mfma_f32_32x32x16_bf16(a[kb], *(const bhalf8*)(B + boff + (kb << 9)), acc, 0, 0, 0);
  return acc;
}

__device__ __forceinline__ void loadA(const short* __restrict__ X, int aoff, bhalf8 a[4]) {
#pragma unroll
  for (int kb = 0; kb < 4; kb++) a[kb] = *(const bhalf8*)(X + aoff + (kb << 9));
}

__device__ __forceinline__ void tstoreH(short* __restrict__ X, int R, int C, int ln, int hf,
                                        const f32x16 v) {
#pragma unroll
  for (int g = 0; g < 4; g++) {
    short4 s;
    s.x = bfh(v[4 * g + 0]); s.y = bfh(v[4 * g + 1]);
    s.z = bfh(v[4 * g + 2]); s.w = bfh(v[4 * g + 3]);
    int addr = (C << 11) + ((2 * R + (g >> 1)) << 9) + ((g & 1) << 8) + (ln << 3) + (hf << 2);
    *(short4*)(X + addr) = s;
  }
}

__device__ __forceinline__ void tstoreHL(short* __restrict__ Xh, short* __restrict__ Xl,
                                         int R, int C, int ln, int hf, const f32x16 v) {
#pragma unroll
  for (int g = 0; g < 4; g++) {
    short4 sh, sl;
#pragma unroll
    for (int t = 0; t < 4; t++) {
      float x = v[4 * g + t];
      unsigned u = __float_as_uint(x) + 0x8000u;
      float l = x - __uint_as_float(u & 0xffff0000u);
      short hv = (short)(u >> 16), lv = bfh(l);
      if (t == 0) { sh.x = hv; sl.x = lv; } else if (t == 1) { sh.y = hv; sl.y = lv; }
      else if (t == 2) { sh.z = hv; sl.z = lv; } else { sh.w = hv; sl.w = lv; }
    }
    int addr = (C << 11) + ((2 * R + (g >> 1)) << 9) + ((g & 1) << 8) + (ln << 3) + (hf << 2);
    *(short4*)(Xh + addr) = sh;
    *(short4*)(Xl + addr) = sl;
  }
}

// ---------- fp32 helpers for the tiny single-matrix kernels ----------

__device__ __forceinline__ void stage64(const float* __restrict__ g, float* __restrict__ s, int tid) {
#pragma unroll
  for (int r = 0; r < 4; r++) {
    int idx = tid + 256 * r;
    *(float4*)(s + 4 * idx) = *(const float4*)(g + 4 * idx);
  }
}

__device__ __forceinline__ void store_tile(float* __restrict__ S, int r0, int c0, const float t[16]) {
#pragma unroll
  for (int i = 0; i < 4; i++)
    *(float4*)(S + (r0 + i) * 64 + c0) = *(const float4*)(&t[4 * i]);
}

// C = A^T B (== A*B for symmetric A)
__device__ __forceinline__ void gemm_tile_sym(const float* __restrict__ A, const float* __restrict__ B,
                                              int r0, int c0, float t[16]) {
#pragma unroll
  for (int i = 0; i < 16; i++) t[i] = 0.f;
#pragma unroll 4
  for (int k = 0; k < 64; k += 4) {
    float a[16], b[16];
#pragma unroll
    for (int kk = 0; kk < 4; kk++) {
      *(float4*)(&a[4 * kk]) = *(const float4*)(A + (k + kk) * 64 + r0);
      *(float4*)(&b[4 * kk]) = *(const float4*)(B + (k + kk) * 64 + c0);
    }
#pragma unroll
    for (int kk = 0; kk < 4; kk++)
#pragma unroll
      for (int i = 0; i < 4; i++)
#pragma unroll
        for (int j = 0; j < 4; j++)
          t[4 * i + j] += a[4 * kk + i] * b[4 * kk + j];
  }
}

// ---------- batch mean ----------

__global__ __launch_bounds__(256) void reduce_mean8(const float* __restrict__ data,
                                                    float* __restrict__ part) {
  const size_t base = (size_t)blockIdx.x * 8 * 4096;
  const int tid = threadIdx.x;
#pragma unroll
  for (int r = 0; r < 4; r++) {
    int idx = tid + 256 * r;
    float4 s = make_float4(0.f, 0.f, 0.f, 0.f);
#pragma unroll
    for (int m = 0; m < 8; m++) {
      float4 v = *(const float4*)(data + base + (size_t)m * 4096 + 4 * idx);
      s.x += v.x; s.y += v.y; s.z += v.z; s.w += v.w;
    }
    *(float4*)(part + (size_t)blockIdx.x * 4096 + 4 * idx) = s;
  }
}

__global__ __launch_bounds__(256) void reduce_cols(const float* __restrict__ part,
                                                   float* __restrict__ outv,
                                                   int nparts, float scale) {
  const int j = blockIdx.x * 256 + threadIdx.x;
  float s = 0.f;
  for (int g = 0; g < nparts; g++) s += part[(size_t)g * 4096 + j];
  outv[j] = s * scale;
}

// ---------- THE hot kernel: batched logm, MFMA + Paterson-Stockmeyer s=4,Q=12 ----------
// Per matrix: W = Mi*D*Mi (2 products; Mi in hi+lo bf16 since its error is systematic),
// T_r recurrence r=2..4 (3 products), matrix-Clenshaw in Y=T_4 (12 products).
// All intermediates single-bf16: per-matrix rounding noise averages out over 8192.

__global__ void __launch_bounds__(256)
__attribute__((amdgpu_waves_per_eu(2, 2)))
cheb4(const float* __restrict__ data, const float* __restrict__ Mi,
      float* __restrict__ partial, PS4 co) {
  __shared__ __align__(16) short sMh[4096], sMl[4096], sX0[4096], sX1[4096];   // 32 KB

  const int tid = threadIdx.x;
  const int lane = tid & 63, wv = tid >> 6;
  const int R = wv >> 1, C = wv & 1;
  const int ln = lane & 31, hf = lane >> 5;
  const int aoffA = (R << 11) + (hf << 8) + (ln << 3);
  const int boffB = (C << 11) + (hf << 8) + (ln << 3);
  const int scol = tid & 63, sq = tid >> 6;
  const int sbase = ((scol >> 5) << 11) + (sq << 9) + ((scol & 31) << 3);

  f32x16 dg;
#pragma unroll
  for (int g = 0; g < 4; g++)
#pragma unroll
    for (int t = 0; t < 4; t++)
      dg[4 * g + t] = ((32 * R + 8 * g + 4 * hf + t) == (32 * C + ln)) ? 1.f : 0.f;

  // stage Mi (hi+lo)
  {
    const float* gp = Mi + scol * 64 + sq * 16;
    bhalf8 h0, h1, l0, l1;
#pragma unroll
    for (int i = 0; i < 8; i++) {
      float x = gp[i], y = gp[8 + i];
      unsigned ux = __float_as_uint(x) + 0x8000u;
      h0[i] = (short)(ux >> 16);
      l0[i] = bfh(x - __uint_as_float(ux & 0xffff0000u));
      unsigned uy = __float_as_uint(y) + 0x8000u;
      h1[i] = (short)(uy >> 16);
      l1[i] = bfh(y - __uint_as_float(uy & 0xffff0000u));
    }
    *(bhalf8*)(sMh + sbase) = h0; *(bhalf8*)(sMh + sbase + 256) = h1;
    *(bhalf8*)(sMl + sbase) = l0; *(bhalf8*)(sMl + sbase + 256) = l1;
  }
  __syncthreads();

  bhalf8 aMh[4], aMl[4];
  loadA(sMh, aoffA, aMh);
  loadA(sMl, aoffA, aMl);

  f32x16 accTm;
#pragma unroll
  for (int t = 0; t < 16; t++) accTm[t] = 0.f;

  const float* dptr = data + (size_t)blockIdx.x * 8 * 4096 + scol * 64 + sq * 16;
  float4 dv0 = *(const float4*)(dptr);
  float4 dv1 = *(const float4*)(dptr + 4);
  float4 dv2 = *(const float4*)(dptr + 8);
  float4 dv3 = *(const float4*)(dptr + 12);

#pragma unroll 1
  for (int m = 0; m < 8; m++) {
    // stage D (hi only) from prefetched regs
    {
      float xs[16] = {dv0.x, dv0.y, dv0.z, dv0.w, dv1.x, dv1.y, dv1.z, dv1.w,
                      dv2.x, dv2.y, dv2.z, dv2.w, dv3.x, dv3.y, dv3.z, dv3.w};
      bhalf8 h0, h1;
#pragma unroll
      for (int i = 0; i < 8; i++) { h0[i] = bfh(xs[i]); h1[i] = bfh(xs[8 + i]); }
      *(bhalf8*)(sX0 + sbase) = h0;
      *(bhalf8*)(sX0 + sbase + 256) = h1;
    }
    __syncthreads();
    if (m < 7) {
      dptr += 4096;
      dv0 = *(const float4*)(dptr);
      dv1 = *(const float4*)(dptr + 4);
      dv2 = *(const float4*)(dptr + 8);
      dv3 = *(const float4*)(dptr + 12);
    }

    // P1: V = D * Mi   (A = D, B = Mi hi+lo)
    bhalf8 aD[4];
    loadA(sX0, aoffA, aD);
    f32x16 acc = gemmA(aD, sMh, boffB);
    f32x16 acc2 = gemmA(aD, sMl, boffB);
#pragma unroll
    for (int t = 0; t < 16; t++) acc[t] += acc2[t];
    tstoreH(sX1, R, C, ln, hf, acc);            // V
    __syncthreads();

    // P2: W = Mi * V  (A = Mi hi+lo, B = V)
    acc = gemmA(aMh, sX1, boffB);
    acc2 = gemmA(aMl, sX1, boffB);
    f32x16 T1;
#pragma unroll
    for (int t = 0; t < 16; t++) T1[t] = (acc[t] + acc2[t] - co.mid * dg[t]) * co.invhalf;
    tstoreH(sX0, R, C, ln, hf, T1);             // What
    __syncthreads();

    bhalf8 aW[4];
    loadA(sX0, aoffA, aW);
    // r=2: T2 = 2 What^2 - I (B also from sX0)
    acc = gemmA(aW, sX0, boffB);
    f32x16 T2;
#pragma unroll
    for (int t = 0; t < 16; t++) T2[t] = 2.f * acc[t] - dg[t];
    tstoreH(sX1, R, C, ln, hf, T2);
    __syncthreads();
    // r=3
    acc = gemmA(aW, sX1, boffB);
    f32x16 T3;
#pragma unroll
    for (int t = 0; t < 16; t++) T3[t] = 2.f * acc[t] - T1[t];
    tstoreH(sX0, R, C, ln, hf, T3);
    __syncthreads();
    // r=4 -> Y
    acc = gemmA(aW, sX0, boffB);
    f32x16 Y;
#pragma unroll
    for (int t = 0; t < 16; t++) Y[t] = 2.f * acc[t] - T2[t];
    tstoreH(sX1, R, C, ln, hf, Y);
    __syncthreads();
    bhalf8 aY[4];
    loadA(sX1, aoffA, aY);

    // Clenshaw in Y with matrix coefficients G_q
    f32x16 bq1, bq2;
#pragma unroll
    for (int t = 0; t < 16; t++) {
      bq1[t] = co.a[PS_Q][0] * dg[t] + co.a[PS_Q][1] * T1[t]
             + co.a[PS_Q][2] * T2[t] + co.a[PS_Q][3] * T3[t];
      bq2[t] = 0.f;
    }
    tstoreH(sX0, R, C, ln, hf, bq1);
    __syncthreads();

    const short* rb = sX0;
    short* wb = sX1;
#pragma unroll
    for (int q = PS_Q - 1; q >= 1; q--) {
      acc = gemmA(aY, rb, boffB);
      f32x16 nb;
#pragma unroll
      for (int t = 0; t < 16; t++)
        nb[t] = co.a[q][0] * dg[t] + co.a[q][1] * T1[t] + co.a[q][2] * T2[t] + co.a[q][3] * T3[t]
              + 2.f * acc[t] - bq2[t];
      bq2 = bq1; bq1 = nb;
      tstoreH(wb, R, C, ln, hf, nb);
      __syncthreads();
      const short* tp = rb; rb = wb; wb = (short*)tp;
    }
    // result = G_0 + Y*b1 - b2
    acc = gemmA(aY, rb, boffB);
#pragma unroll
    for (int t = 0; t < 16; t++)
      accTm[t] += co.a[0][0] * dg[t] + co.a[0][1] * T1[t] + co.a[0][2] * T2[t] + co.a[0][3] * T3[t]
                + acc[t] - bq2[t];
    // next iteration's staging writes sX0; last sX0 reads were before the q=1 barrier. safe.
  }

  float* pp = partial + (size_t)blockIdx.x * 4096;
#pragma unroll
  for (int g = 0; g < 4; g++)
#pragma unroll
    for (int t = 0; t < 4; t++)
      pp[(32 * R + 8 * g + 4 * hf + t) * 64 + (32 * C + ln)] = accTm[4 * g + t];
}

// ---------- out_b = P * D_b * P^T via MFMA (hi/lo triple: per-matrix output, no averaging) ----------

__global__ void __launch_bounds__(256)
__attribute__((amdgpu_waves_per_eu(2, 2)))
final_mfma(const float* __restrict__ data, const float* __restrict__ Pm,
           float* __restrict__ out) {
  __shared__ __align__(16) short sPh[4096], sPl[4096], sDh[4096], sDl[4096], sVh[4096], sVl[4096];

  const int tid = threadIdx.x;
  const int lane = tid & 63, wv = tid >> 6;
  const int R = wv >> 1, C = wv & 1;
  const int ln = lane & 31, hf = lane >> 5;
  const int aoffA = (R << 11) + (hf << 8) + (ln << 3);
  const int boffB = (C << 11) + (hf << 8) + (ln << 3);
  const int scol = tid & 63, sq = tid >> 6;
  const int sbase = ((scol >> 5) << 11) + (sq << 9) + ((scol & 31) << 3);

  // stage P (hi+lo): B-frags give P^T, A-frags give P
  {
    const float* gp = Pm + scol * 64 + sq * 16;
    bhalf8 h0, h1, l0, l1;
#pragma unroll
    for (int i = 0; i < 8; i++) {
      float x = gp[i], y = gp[8 + i];
      unsigned ux = __float_as_uint(x) + 0x8000u;
      h0[i] = (short)(ux >> 16);
      l0[i] = bfh(x - __uint_as_float(ux & 0xffff0000u));
      unsigned uy = __float_as_uint(y) + 0x8000u;
      h1[i] = (short)(uy >> 16);
      l1[i] = bfh(y - __uint_as_float(uy & 0xffff0000u));
    }
    *(bhalf8*)(sPh + sbase) = h0; *(bhalf8*)(sPh + sbase + 256) = h1;
    *(bhalf8*)(sPl + sbase) = l0; *(bhalf8*)(sPl + sbase + 256) = l1;
  }
  __syncthreads();

  bhalf8 aPh[4], aPl[4];
  loadA(sPh, aoffA, aPh);
  loadA(sPl, aoffA, aPl);

  const float* dptr = data + (size_t)blockIdx.x * 8 * 4096 + scol * 64 + sq * 16;
  float4 dv0 = *(const float4*)(dptr);
  float4 dv1 = *(const float4*)(dptr + 4);
  float4 dv2 = *(const float4*)(dptr + 8);
  float4 dv3 = *(const float4*)(dptr + 12);

#pragma unroll 1
  for (int m = 0; m < 8; m++) {
    {
      float xs[16] = {dv0.x, dv0.y, dv0.z, dv0.w, dv1.x, dv1.y, dv1.z, dv1.w,
                      dv2.x, dv2.y, dv2.z, dv2.w, dv3.x, dv3.y, dv3.z, dv3.w};
      bhalf8 h0, h1, l0, l1;
#pragma unroll
      for (int i = 0; i < 8; i++) {
        float x = xs[i], y = xs[8 + i];
        unsigned ux = __float_as_uint(x) + 0x8000u;
        h0[i] = (short)(ux >> 16);
        l0[i] = bfh(x - __uint_as_float(ux & 0xffff0000u));
        unsigned uy = __float_as_uint(y) + 0x8000u;
        h1[i] = (short)(uy >> 16);
        l1[i] = bfh(y - __uint_as_float(uy & 0xffff0000u));
      }
      *(bhalf8*)(sDh + sbase) = h0; *(bhalf8*)(sDh + sbase + 256) = h1;
      *(bhalf8*)(sDl + sbase) = l0; *(bhalf8*)(sDl + sbase + 256) = l1;
    }
    __syncthreads();
    if (m < 7) {
      dptr += 4096;
      dv0 = *(const float4*)(dptr);
      dv1 = *(const float4*)(dptr + 4);
      dv2 = *(const float4*)(dptr + 8);
      dv3 = *(const float4*)(dptr + 12);
    }

    // P1: V = D * P^T  (triple split)
    bhalf8 aDh[4], aDl[4];
    loadA(sDh, aoffA, aDh);
    loadA(sDl, aoffA, aDl);
    f32x16 a1 = gemmA(aDh, sPh, boffB);
    f32x16 a2 = gemmA(aDh, sPl, boffB);
    f32x16 a3 = gemmA(aDl, sPh, boffB);
#pragma unroll
    for (int t = 0; t < 16; t++) a1[t] += a2[t] + a3[t];
    tstoreHL(sVh, sVl, R, C, ln, hf, a1);
    __syncthreads();

    // P2: out = P * V  (triple split)
    a1 = gemmA(aPh, sVh, boffB);
    a2 = gemmA(aPh, sVl, boffB);
    a3 = gemmA(aPl, sVh, boffB);
#pragma unroll
    for (int t = 0; t < 16; t++) a1[t] += a2[t] + a3[t];
    float* ob = out + ((size_t)blockIdx.x * 8 + m) * 4096;
#pragma unroll
    for (int g = 0; g < 4; g++)
#pragma unroll
    for (int t = 0; t < 4; t++)
      ob[(32 * R + 8 * g + 4 * hf + t) * 64 + (32 * C + ln)] = a1[4 * g + t];
    __syncthreads();   // sV reads done before next iteration's sD staging + sV overwrite
  }
}

// ---------- single-matrix kernels (fp32) ----------

__global__ __launch_bounds__(256) void invsqrt_series(const float* __restrict__ Min,
                                                      float* __restrict__ MiOut,
                                                      float* __restrict__ MsOut) {
  __shared__ float sM[4096], sE[4096], sE2[4096], sE3[4096];
  __shared__ float csh;
  const int tid = threadIdx.x;
  const int r0 = (tid >> 4) << 2, c0 = (tid & 15) << 2;

  stage64(Min, sM, tid);
  __syncthreads();
  if (tid == 0) {
    float s = 0.f;
    for (int i = 0; i < 64; i++) s += sM[i * 64 + i];
    csh = s * (1.f / 64.f);
  }
  __syncthreads();
  const float invc = 1.f / csh;
  for (int idx = tid; idx < 4096; idx += 256) {
    int r = idx >> 6, c = idx & 63;
    sE[idx] = 0.5f * (sM[idx] + sM[c * 64 + r]) * invc - ((r == c) ? 1.f : 0.f);
  }
  __syncthreads();

  float t[16];
  gemm_tile_sym(sE, sE, r0, c0, t);  store_tile(sE2, r0, c0, t); __syncthreads();
  gemm_tile_sym(sE2, sE, r0, c0, t); store_tile(sE3, r0, c0, t); __syncthreads();
  gemm_tile_sym(sE2, sE2, r0, c0, t); store_tile(sM, r0, c0, t); __syncthreads();
  float t5[16];
  gemm_tile_sym(sE2, sE3, r0, c0, t5);

  const float sc = sqrtf(csh), rsc = 1.f / sc;
#pragma unroll
  for (int i = 0; i < 4; i++)
#pragma unroll
    for (int j = 0; j < 4; j++) {
      int off = (r0 + i) * 64 + (c0 + j);
      float d = ((r0 + i) == (c0 + j)) ? 1.f : 0.f;
      float e = sE[off], e2 = sE2[off], e3 = sE3[off], e4 = sM[off], e5 = t5[4 * i + j];
      float mi = (d - 0.5f * e + 0.375f * e2 - 0.3125f * e3 + 0.2734375f * e4 - 0.24609375f * e5) * rsc;
      float ms = (d + 0.5f * e - 0.125f * e2 + 0.0625f * e3 - 0.0390625f * e4 + 0.02734375f * e5) * sc;
      MiOut[off] = mi;
      MsOut[off] = ms;
    }
}

__device__ void taylor_expm8(const float* __restrict__ sA, float* __restrict__ sR,
                             int tid, int r0, int c0, float postscale) {
  for (int idx = tid; idx < 4096; idx += 256) {
    int r = idx >> 6, c = idx & 63;
    sR[idx] = ((r == c) ? 1.f : 0.f) + sA[idx] * 0.125f;
  }
  __syncthreads();
  float t[16];
#pragma unroll 1
  for (int k = 7; k >= 1; k--) {
    gemm_tile_sym(sA, sR, r0, c0, t);
    __syncthreads();
    const float inv = 1.f / (float)k;
    const float fin = (k == 1) ? postscale : 1.f;
#pragma unroll
    for (int i = 0; i < 4; i++)
#pragma unroll
      for (int j = 0; j < 4; j++) {
        int off = (r0 + i) * 64 + (c0 + j);
        float d = ((r0 + i) == (c0 + j)) ? 1.f : 0.f;
        sR[off] = (d + t[4 * i + j] * inv) * fin;
      }
    __syncthreads();
  }
}

// M <- Ms * expm(sym(T)) * Ms, then (Mi, Ms) <- invsqrt/sqrt series of M. One block.
__global__ __launch_bounds__(256) void update_fused(const float* __restrict__ Tin,
                                                    float* __restrict__ Ms_io,
                                                    float* __restrict__ Mout,
                                                    float* __restrict__ MiOut) {
  __shared__ float b0[4096], b1[4096], b2[4096], b3[4096];
  __shared__ float sh_mu, sh_c;
  const int tid = threadIdx.x;
  const int r0 = (tid >> 4) << 2, c0 = (tid & 15) << 2;

  // ---- phase 1: expm update ----
  stage64(Tin, b2, tid);
  __syncthreads();
  if (tid == 0) {
    float s = 0.f;
    for (int i = 0; i < 64; i++) s += b2[i * 64 + i];
    sh_mu = s * (1.f / 64.f);
  }
  __syncthreads();
  const float mu = sh_mu;
  for (int idx = tid; idx < 4096; idx += 256) {
    int r = idx >> 6, c = idx & 63;
    b0[idx] = 0.5f * (b2[idx] + b2[c * 64 + r]) - ((r == c) ? mu : 0.f);
  }
  __syncthreads();
  taylor_expm8(b0, b1, tid, r0, c0, expf(mu));    // b1 = expm(T)

  stage64(Ms_io, b2, tid);
  __syncthreads();
  float t[16];
  gemm_tile_sym(b1, b2, r0, c0, t);               // R*Ms
  store_tile(b0, r0, c0, t);
  __syncthreads();
  gemm_tile_sym(b2, b0, r0, c0, t);               // M = Ms*(R*Ms)
  store_tile(b3, r0, c0, t);
#pragma unroll
  for (int i = 0; i < 4; i++)
    *(float4*)(Mout + (r0 + i) * 64 + c0) = *(const float4*)(&t[4 * i]);
  __syncthreads();

  // ---- phase 2: invsqrt/sqrt series on M (in b3) ----
  if (tid == 0) {
    float s = 0.f;
    for (int i = 0; i < 64; i++) s += b3[i * 64 + i];
    sh_c = s * (1.f / 64.f);
  }
  __syncthreads();
  const float cc = sh_c, invc = 1.f / cc;
  for (int idx = tid; idx < 4096; idx += 256) {
    int r = idx >> 6, c = idx & 63;
    b0[idx] = 0.5f * (b3[idx] + b3[c * 64 + r]) * invc - ((r == c) ? 1.f : 0.f);   // E
  }
  __syncthreads();
  gemm_tile_sym(b0, b0, r0, c0, t);  store_tile(b1, r0, c0, t); __syncthreads();   // E2
  gemm_tile_sym(b1, b0, r0, c0, t);  store_tile(b2, r0, c0, t); __syncthreads();   // E3
  gemm_tile_sym(b1, b1, r0, c0, t);  store_tile(b3, r0, c0, t); __syncthreads();   // E4
  float t5[16];
  gemm_tile_sym(b1, b2, r0, c0, t5);                                               // E5

  const float sc = sqrtf(cc), rsc = 1.f / sc;
#pragma unroll
  for (int i = 0; i < 4; i++)
#pragma unroll
    for (int j = 0; j < 4; j++) {
      int off = (r0 + i) * 64 + (c0 + j);
      float d = ((r0 + i) == (c0 + j)) ? 1.f : 0.f;
      float e = b0[off], e2 = b1[off], e3 = b2[off], e4 = b3[off], e5 = t5[4 * i + j];
      float mi = (d - 0.5f * e + 0.375f * e2 - 0.3125f * e3 + 0.2734375f * e4 - 0.24609375f * e5) * rsc;
      float ms = (d + 0.5f * e - 0.125f * e2 + 0.0625f * e3 - 0.0390625f * e4 + 0.02734375f * e5) * sc;
      MiOut[off] = mi;
      Ms_io[off] = ms;
    }
}

// S = expm(sym(bias)/2), P = S*G
__global__ __launch_bounds__(256) void bias_expm_P(const float* __restrict__ bias,
                                                   const float* __restrict__ Gin,
                                                   float* __restrict__ Pout) {
  __shared__ float sA[4096], sR[4096], sB[4096];
  const int tid = threadIdx.x;
  const int r0 = (tid >> 4) << 2, c0 = (tid & 15) << 2;

  stage64(bias, sB, tid);
  __syncthreads();
  for (int idx = tid; idx < 4096; idx += 256) {
    int r = idx >> 6, c = idx & 63;
    sA[idx] = 0.0625f * (sB[idx] + sB[c * 64 + r]);
  }
  __syncthreads();
  taylor_expm8(sA, sR, tid, r0, c0, 1.f);

  float t[16];
  gemm_tile_sym(sR, sR, r0, c0, t);
  store_tile(sB, r0, c0, t);
  __syncthreads();
  gemm_tile_sym(sB, sB, r0, c0, t);
  store_tile(sR, r0, c0, t);
  stage64(Gin, sA, tid);
  __syncthreads();
  gemm_tile_sym(sR, sA, r0, c0, t);
#pragma unroll
  for (int i = 0; i < 4; i++)
    *(float4*)(Pout + (r0 + i) * 64 + c0) = *(const float4*)(&t[4 * i]);
}

// ---------- launch ----------

extern "C" void kernel_launch(void* const* d_in, const int* in_sizes, int n_in,
                              void* d_out, int out_size, void* d_ws, size_t ws_size,
                              hipStream_t stream) {
  const float* data = (const float*)d_in[0];
  const float* bias = (const float*)d_in[1];
  float* out = (float*)d_out;

  float* part = out;                 // 16 MB partial scratch inside d_out (overwritten by final pass)
  float* M  = (float*)d_ws;
  float* Mi = M + 4096;
  float* Ms = Mi + 4096;
  float* Tm = Ms + 4096;
  float* Pm = Tm + 4096;

  // Chebyshev coefficients of log on [a,b] + exact Paterson-Stockmeyer refactor (s=4, Q=12)
  PS4 co;
  {
    const double a = A_CHEB, b = B_CHEB;
    const int N = 512;
    double c[64] = {0};
    for (int j = 0; j <= K_CHEB; j++) {
      double s = 0.0;
      for (int k = 0; k < N; k++) {
        double th = M_PI * (k + 0.5) / N;
        double x = 0.5 * (a + b) + 0.5 * (b - a) * std::cos(th);
        s += std::log(x) * std::cos(j * th);
      }
      c[j] = 2.0 * s / N;
    }
    c[0] *= 0.5;
    double aa[PS_Q + 1][PS_S] = {};
    for (int q = PS_Q; q >= 1; --q) {
      for (int r = PS_S - 1; r >= 1; --r) {
        int k = q * PS_S + r;
        double av = 2.0 * c[k];
        aa[q][r] = av;
        c[k] -= av * 0.5;
        c[q * PS_S - r] -= av * 0.5;   // T_r * T_{qS} = (T_{qS+r} + T_{qS-r})/2
      }
      aa[q][0] = c[q * PS_S];
      c[q * PS_S] = 0.0;
    }
    for (int r = 0; r < PS_S; r++) aa[0][r] = c[r];
    co.mid = (float)(0.5 * (a + b));
    co.invhalf = (float)(2.0 / (b - a));
    for (int q = 0; q <= PS_Q; q++)
      for (int r = 0; r < PS_S; r++) co.a[q][r] = (float)aa[q][r];
  }

  reduce_mean8<<<1024, 256, 0, stream>>>(data, part);
  reduce_cols<<<16, 256, 0, stream>>>(part, M, 1024, 1.f / 8192.f);
  invsqrt_series<<<1, 256, 0, stream>>>(M, Mi, Ms);

  for (int it = 0; it < 3; ++it) {
    cheb4<<<1024, 256, 0, stream>>>(data, Mi, part, co);
    reduce_cols<<<16, 256, 0, stream>>>(part, Tm, 1024, 1.f / 8192.f);
    update_fused<<<1, 256, 0, stream>>>(Tm, Ms, M, Mi);   // last iter: Mi = G
  }

  bias_expm_P<<<1, 256, 0, stream>>>(bias, Mi, Pm);
  final_mfma<<<1024, 256, 0, stream>>>(data, Pm, out);
}